// Round 5
// baseline (102.480 us; speedup 1.0000x reference)
//
#include <hip/hip_runtime.h>

// ---------------------------------------------------------------------------
// DWT autoencoder round trip. Level-2 dwt2+idwt2 cancel exactly -> LL1r==LL1.
//   K0: rearrange conv weights into exact consumption order
//   K1: per-channel LDS staging of the RAW x tile (66x68 = 18KB), coalesced
//       float4 stage; haar bands + 3x3 s2 conv computed from LDS.
//       Writes LL1 (B,3,256,256) + y (B,9,128,128).
//   K2: convT4x4 s2 of y -> l1 bands, fused with idwt2(LL1, l1) -> out
// B=32, C=3, H=W=512.
// R4 lesson: register-only K1 = 18 uncoalesced f2 loads/thread, latency-bound
// at 28% occupancy. R3 lesson: 39KB band-LDS capped residency at 4 blocks/CU.
// This round: small raw-x LDS (18KB) + coalesced staging + branch-free math.
// ---------------------------------------------------------------------------

#define BB 32

// K0: wd[((ch*3+a)*3+q)*27 + band*9 + o] = 0.5 * dw[o, ch*3+band, a, q]
//     (0.5 = DWT band scale folded into the conv weight)
//     wu[((cin*4+rt*2+ct)*4+di*2+dj)*9+o] = uw[cin, o, 3-di-2rt, 3-dj-2ct]
__global__ __launch_bounds__(256) void k0_rearrange(
    const float* __restrict__ dw, const float* __restrict__ uw,
    float* __restrict__ wd, float* __restrict__ wu)
{
    const int t = threadIdx.x;
    for (int i = t; i < 729; i += 256) {
        const int o    = i % 9;
        const int band = (i / 9) % 3;
        const int q    = (i / 27) % 3;
        const int a    = (i / 81) % 3;
        const int ch   = i / 243;
        wd[i] = 0.5f * dw[o * 81 + (ch * 3 + band) * 9 + a * 3 + q];
    }
    for (int i = t; i < 1296; i += 256) {
        const int o = i % 9; int r = i / 9;
        const int dj = r & 1; const int di = (r >> 1) & 1; r >>= 2;
        const int ct = r & 1; const int rt = (r >> 1) & 1; const int cin = r >> 2;
        wu[i] = uw[cin * 144 + o * 16 + (3 - di - 2 * rt) * 4 + (3 - dj - 2 * ct)];
    }
}

// K1: block = 16x16 y-tile of one batch image. Per channel: stage x rows
// [4i0-2, 4i0+63] x cols [4j0-4, 4j0+63] (zero-filled halo) into LDS with
// float4, then each thread computes its 6x6 window's bands + 81 FMAs.
__global__ __launch_bounds__(256) void k1_dwt_down(
    const float* __restrict__ x,     // (B,3,512,512)
    const float* __restrict__ wd,    // reordered (ch,a,q,band,o), x0.5 folded
    const float* __restrict__ db,    // (9)
    float* __restrict__ LL1,         // (B,3,256,256)
    float* __restrict__ y)           // (B,9,128,128)
{
    __shared__ float xs[66][68];     // 17.95 KB

    const int t    = threadIdx.x;
    const int b    = blockIdx.x >> 6;
    const int tile = blockIdx.x & 63;
    const int i0   = (tile >> 3) << 4;   // y tile origin
    const int j0   = (tile & 7) << 4;
    const int ti   = t >> 4;             // 0..15
    const int tj   = t & 15;             // 0..15
    const int I    = i0 + ti;
    const int J    = j0 + tj;

    const int gr0 = 4 * i0 - 2;          // global x row of LDS row 0
    const int gc0 = 4 * j0 - 4;          // global x col of LDS col 0 (16B aligned)

    float acc[9];
#pragma unroll
    for (int o = 0; o < 9; ++o) acc[o] = db[o];

    for (int ch = 0; ch < 3; ++ch) {
        const float* xc = x + ((size_t)b * 3 + ch) * 512 * 512;

        if (ch) __syncthreads();         // protect previous compute reads
        // ---- stage: 66 rows x 17 float4 = 1122 items ----
        for (int idx = t; idx < 1122; idx += 256) {
            const int lr = idx / 17;
            const int f4 = idx - lr * 17;
            const int gr = gr0 + lr;
            float4 v = make_float4(0.f, 0.f, 0.f, 0.f);
            if (gr >= 0 && !(f4 == 0 && j0 == 0))
                v = *reinterpret_cast<const float4*>(xc + (size_t)gr * 512 + gc0 + 4 * f4);
            *reinterpret_cast<float4*>(&xs[lr][4 * f4]) = v;
        }
        __syncthreads();

        // ---- compute: bands from 6x6 window + conv FMAs ----
        const float* wch = wd + ch * 243;
        float* llc = LL1 + ((size_t)b * 3 + ch) * 256 * 256;
#pragma unroll
        for (int a = 0; a < 3; ++a) {
            float2 p[2][3];              // [x-row parity][band-col tap]
#pragma unroll
            for (int rr = 0; rr < 2; ++rr)
#pragma unroll
                for (int k = 0; k < 3; ++k)
                    p[rr][k] = *reinterpret_cast<const float2*>(
                        &xs[4 * ti + 2 * a + rr][4 * tj + 2 + 2 * k]);

            float lh[3], hl[3], hh[3], llv1, llv2;
            {
                const float s0 = p[0][0].x + p[0][0].y, d0 = p[0][0].x - p[0][0].y;
                const float s1 = p[1][0].x + p[1][0].y, d1 = p[1][0].x - p[1][0].y;
                lh[0] = s0 - s1; hl[0] = d0 + d1; hh[0] = d0 - d1;
            }
            {
                const float s0 = p[0][1].x + p[0][1].y, d0 = p[0][1].x - p[0][1].y;
                const float s1 = p[1][1].x + p[1][1].y, d1 = p[1][1].x - p[1][1].y;
                lh[1] = s0 - s1; hl[1] = d0 + d1; hh[1] = d0 - d1;
                llv1 = (s0 + s1) * 0.5f;
            }
            {
                const float s0 = p[0][2].x + p[0][2].y, d0 = p[0][2].x - p[0][2].y;
                const float s1 = p[1][2].x + p[1][2].y, d1 = p[1][2].x - p[1][2].y;
                lh[2] = s0 - s1; hl[2] = d0 + d1; hh[2] = d0 - d1;
                llv2 = (s0 + s1) * 0.5f;
            }

            // LL1: level-1 row r=2I-1+a (a>=1), cols {2J, 2J+1}
            if (a >= 1) {
                float2 w2; w2.x = llv1; w2.y = llv2;
                *reinterpret_cast<float2*>(llc + (size_t)(2 * I - 1 + a) * 256 + 2 * J) = w2;
            }

            const float* wg = wch + a * 81;
#pragma unroll
            for (int q = 0; q < 3; ++q) {
                const float* w0 = wg + q * 27;   // 27 consecutive uniform weights
#pragma unroll
                for (int o = 0; o < 9; ++o) acc[o] += lh[q] * w0[o];
#pragma unroll
                for (int o = 0; o < 9; ++o) acc[o] += hl[q] * w0[9 + o];
#pragma unroll
                for (int o = 0; o < 9; ++o) acc[o] += hh[q] * w0[18 + o];
            }
        }
    }

#pragma unroll
    for (int o = 0; o < 9; ++o)
        y[(((size_t)b * 9 + o) * 128 + I) * 128 + J] = acc[o];
}

// K2: one block = one batch image, a 32x32 tile at 256-res (=> 64x64 output
// pixels at 512-res), all 3 colors. Each thread owns a 2x2 parity quad; all
// 36 accumulators live (needs VGPR room -> launch_bounds(256,4)).
__global__ __launch_bounds__(256, 4) void k2_up_idwt(
    const float* __restrict__ yg,    // (B,9,128,128)
    const float* __restrict__ wu,    // reordered (cin,rt,ct,di,dj,o)
    const float* __restrict__ ub,    // (9)
    const float* __restrict__ LL1,   // (B,3,256,256)
    float* __restrict__ out)         // (B,3,512,512)
{
    __shared__ float ysh[9][18][19];

    const int t    = threadIdx.x;
    const int b    = blockIdx.x >> 6;
    const int tile = blockIdx.x & 63;
    const int r0   = (tile >> 3) << 5;  // 256-res tile origin
    const int c0   = (tile & 7) << 5;
    const int p0   = (r0 >> 1) - 1;     // y row of local 0
    const int q0   = (c0 >> 1) - 1;

    // ---- stage y tile (18x18 halo, 9 ch) into LDS ----
    for (int item = t; item < 9 * 324; item += 256) {
        const int cin = item / 324;
        int rem       = item - cin * 324;
        const int lp  = rem / 18;
        const int lq  = rem - lp * 18;
        const int p   = p0 + lp, q = q0 + lq;
        float v = 0.f;
        if (p >= 0 && p < 128 && q >= 0 && q < 128)
            v = yg[(((size_t)b * 9 + cin) * 128 + p) * 128 + q];
        ysh[cin][lp][lq] = v;
    }
    __syncthreads();

    const int i2 = t >> 4;   // 0..15
    const int j2 = t & 15;   // 0..15

    float acc[2][2][9];      // [di][dj][out-ch]
#pragma unroll
    for (int di = 0; di < 2; ++di)
#pragma unroll
        for (int dj = 0; dj < 2; ++dj)
#pragma unroll
            for (int o = 0; o < 9; ++o) acc[di][dj][o] = ub[o];

    for (int cin = 0; cin < 9; ++cin) {
        float yv[3][3];
#pragma unroll
        for (int r = 0; r < 3; ++r)
#pragma unroll
            for (int c = 0; c < 3; ++c)
                yv[r][c] = ysh[cin][i2 + r][j2 + c];
        const float* wc = wu + cin * 144;
#pragma unroll
        for (int rt = 0; rt < 2; ++rt)
#pragma unroll
            for (int ct = 0; ct < 2; ++ct) {
                const float* wg = wc + (rt * 2 + ct) * 36;  // 36 consecutive
#pragma unroll
                for (int di = 0; di < 2; ++di)
#pragma unroll
                    for (int dj = 0; dj < 2; ++dj) {
                        const float vv = yv[di + rt][dj + ct];
                        const float* w9 = wg + (di * 2 + dj) * 9;
#pragma unroll
                        for (int o = 0; o < 9; ++o)
                            acc[di][dj][o] += vv * w9[o];
                    }
            }
    }

    // ---- epilogue: idwt2(LL1, LH, HL, HH) -> 4x4 output pixels / color ----
#pragma unroll
    for (int cc = 0; cc < 3; ++cc) {
#pragma unroll
        for (int di = 0; di < 2; ++di) {
            const int I = r0 + 2 * i2 + di;
            const int J = c0 + 2 * j2;
            const float2 llv = *reinterpret_cast<const float2*>(
                LL1 + (((size_t)b * 3 + cc) * 256 + I) * 256 + J);
            float4 top, bot;
            {
                const float ll = llv.x;
                const float lh = acc[di][0][cc * 3 + 0];
                const float hl = acc[di][0][cc * 3 + 1];
                const float hh = acc[di][0][cc * 3 + 2];
                const float e0 = ll + lh, od0 = ll - lh;
                const float e1 = hl + hh, od1 = hl - hh;
                top.x = (e0 + e1) * 0.5f; top.y = (e0 - e1) * 0.5f;
                bot.x = (od0 + od1) * 0.5f; bot.y = (od0 - od1) * 0.5f;
            }
            {
                const float ll = llv.y;
                const float lh = acc[di][1][cc * 3 + 0];
                const float hl = acc[di][1][cc * 3 + 1];
                const float hh = acc[di][1][cc * 3 + 2];
                const float e0 = ll + lh, od0 = ll - lh;
                const float e1 = hl + hh, od1 = hl - hh;
                top.z = (e0 + e1) * 0.5f; top.w = (e0 - e1) * 0.5f;
                bot.z = (od0 + od1) * 0.5f; bot.w = (od0 - od1) * 0.5f;
            }
            float* op = out + (((size_t)b * 3 + cc) * 512 + 2 * I) * 512 + 2 * J;
            *reinterpret_cast<float4*>(op) = top;
            *reinterpret_cast<float4*>(op + 512) = bot;
        }
    }
}

extern "C" void kernel_launch(void* const* d_in, const int* in_sizes, int n_in,
                              void* d_out, int out_size, void* d_ws, size_t ws_size,
                              hipStream_t stream) {
    const float* x  = (const float*)d_in[0];
    const float* dw = (const float*)d_in[1];
    const float* db = (const float*)d_in[2];
    const float* uw = (const float*)d_in[3];
    const float* ub = (const float*)d_in[4];
    float* outp = (float*)d_out;

    float* wsf = (float*)d_ws;
    float* wd  = wsf;            // 729 floats (pad to 768)
    float* wu  = wsf + 768;      // 1296 floats (pad to 1536)
    float* LL1 = wsf + 2304;                         // 25.2 MB
    float* y   = LL1 + (size_t)BB * 3 * 256 * 256;   // 18.9 MB

    k0_rearrange<<<dim3(1), dim3(256), 0, stream>>>(dw, uw, wd, wu);
    k1_dwt_down<<<dim3(BB * 64), dim3(256), 0, stream>>>(x, wd, db, LL1, y);
    k2_up_idwt<<<dim3(BB * 64), dim3(256), 0, stream>>>(y, wu, ub, LL1, outp);
}

// Round 7
// 91.194 us; speedup vs baseline: 1.1238x; 1.1238x over previous
//
#include <hip/hip_runtime.h>

// ---------------------------------------------------------------------------
// DWT autoencoder round trip. Level-2 dwt2+idwt2 cancel exactly -> LL1r==LL1.
//   K0: rearrange conv weights into consumption order + zero-page init
//   K1: double-buffered global_load_lds staging of raw x (per channel),
//       prefetch ch+1 issued BEFORE compute of ch so HBM latency hides under
//       the 243 FMAs; haar bands + 3x3 s2 conv computed from LDS.
//       gload_lds is issued with ALL lanes active; halo/invalid lanes point
//       their GLOBAL address at a zero-page (per-lane global addr is legal,
//       per-lane LDS addr / exec-masking is NOT -- R6 lesson, m104/m108).
//   K2: convT4x4 s2 of y -> l1 bands, fused with idwt2(LL1, l1) -> out
// B=32, C=3, H=W=512.
// ---------------------------------------------------------------------------

#define BB 32

// K0: wd[((ch*3+a)*3+q)*27 + band*9 + o] = 0.5 * dw[o, ch*3+band, a, q]
//     wu[((cin*4+rt*2+ct)*4+di*2+dj)*9+o] = uw[cin, o, 3-di-2rt, 3-dj-2ct]
//     zp[0..15] = 0 (zero-page for halo gload lanes)
__global__ __launch_bounds__(256) void k0_rearrange(
    const float* __restrict__ dw, const float* __restrict__ uw,
    float* __restrict__ wd, float* __restrict__ wu, float* __restrict__ zp)
{
    const int t = threadIdx.x;
    for (int i = t; i < 729; i += 256) {
        const int o    = i % 9;
        const int band = (i / 9) % 3;
        const int q    = (i / 27) % 3;
        const int a    = (i / 81) % 3;
        const int ch   = i / 243;
        wd[i] = 0.5f * dw[o * 81 + (ch * 3 + band) * 9 + a * 3 + q];
    }
    for (int i = t; i < 1296; i += 256) {
        const int o = i % 9; int r = i / 9;
        const int dj = r & 1; const int di = (r >> 1) & 1; r >>= 2;
        const int ct = r & 1; const int rt = (r >> 1) & 1; const int cin = r >> 2;
        wu[i] = uw[cin * 144 + o * 16 + (3 - di - 2 * rt) * 4 + (3 - dj - 2 * ct)];
    }
    if (t < 16) zp[t] = 0.f;
}

__device__ __forceinline__ void gload16(const float* gp, float* lp) {
    __builtin_amdgcn_global_load_lds(
        (const __attribute__((address_space(1))) void*)gp,
        (__attribute__((address_space(3))) void*)lp, 16, 0, 0);
}

// K1: block = 16x16 y-tile. x tile per channel = 66 rows x 17 float4 = 1122
// slots, linear in LDS. 18 wave-wide gload_lds instructions stage a channel;
// invalid lanes (halo / tail) read the zero-page instead of masking off.
__global__ __launch_bounds__(256) void k1_dwt_down(
    const float* __restrict__ x,     // (B,3,512,512)
    const float* __restrict__ wd,    // reordered (ch,a,q,band,o), x0.5 folded
    const float* __restrict__ db,    // (9)
    const float* __restrict__ zp,    // 16-float zero page
    float* __restrict__ LL1,         // (B,3,256,256)
    float* __restrict__ y)           // (B,9,128,128)
{
    __shared__ float xs[2][4608];    // 2 x 1152 float4 slots (1122 used), 36.9 KB

    const int t    = threadIdx.x;
    const int b    = blockIdx.x >> 6;
    const int tile = blockIdx.x & 63;
    const int i0   = (tile >> 3) << 4;   // y tile origin
    const int j0   = (tile & 7) << 4;
    const int ti   = t >> 4;             // 0..15
    const int tj   = t & 15;             // 0..15
    const int I    = i0 + ti;
    const int J    = j0 + tj;
    const int gr0  = 4 * i0 - 2;         // global x row of LDS row 0
    const int gc0  = 4 * j0 - 4;         // global x col of LDS col 0 (16B aligned)
    const int w    = t >> 6;             // wave id 0..3
    const int lane = t & 63;

    // ---- stage one channel into buffer buf via global_load_lds ----
    // ALL lanes execute every gload; invalid lanes read the zero-page.
    auto stage = [&](int buf, int ch) {
        const float* xc = x + ((size_t)b * 3 + ch) * (512 * 512);
#pragma unroll
        for (int n = 0; n < 5; ++n) {
            const int s = n * 4 + w;          // wave-uniform slot 0..19
            if (s >= 18) break;               // uniform per wave
            const int idx = s * 64 + lane;    // float4 slot this lane fills
            const int lr  = idx / 17;
            const int f4c = idx - lr * 17;
            const int gr  = gr0 + lr;
            const bool ok = (idx < 1122) && (gr >= 0) && !(f4c == 0 && j0 == 0);
            const float* gp = ok ? (xc + (size_t)gr * 512 + gc0 + 4 * f4c) : zp;
            gload16(gp, &xs[buf][idx * 4]);   // unconditional, 64 lanes
        }
    };

    float acc[9];
#pragma unroll
    for (int o = 0; o < 9; ++o) acc[o] = db[o];

    stage(0, 0);
    __syncthreads();                          // buf0 ready (vmcnt drained)

#pragma unroll
    for (int ch = 0; ch < 3; ++ch) {
        if (ch < 2) stage((ch + 1) & 1, ch + 1);   // prefetch next channel
        const int buf = ch & 1;
        const float* wch = wd + ch * 243;
        float* llc = LL1 + ((size_t)b * 3 + ch) * (256 * 256);

#pragma unroll
        for (int a = 0; a < 3; ++a) {
            float2 p[2][3];                   // [x-row parity][band-col tap]
#pragma unroll
            for (int rr = 0; rr < 2; ++rr)
#pragma unroll
                for (int k = 0; k < 3; ++k)
                    p[rr][k] = *reinterpret_cast<const float2*>(
                        &xs[buf][(4 * ti + 2 * a + rr) * 68 + 4 * tj + 2 + 2 * k]);

            float lh[3], hl[3], hh[3], llv1, llv2;
            {
                const float s0 = p[0][0].x + p[0][0].y, d0 = p[0][0].x - p[0][0].y;
                const float s1 = p[1][0].x + p[1][0].y, d1 = p[1][0].x - p[1][0].y;
                lh[0] = s0 - s1; hl[0] = d0 + d1; hh[0] = d0 - d1;
            }
            {
                const float s0 = p[0][1].x + p[0][1].y, d0 = p[0][1].x - p[0][1].y;
                const float s1 = p[1][1].x + p[1][1].y, d1 = p[1][1].x - p[1][1].y;
                lh[1] = s0 - s1; hl[1] = d0 + d1; hh[1] = d0 - d1;
                llv1 = (s0 + s1) * 0.5f;
            }
            {
                const float s0 = p[0][2].x + p[0][2].y, d0 = p[0][2].x - p[0][2].y;
                const float s1 = p[1][2].x + p[1][2].y, d1 = p[1][2].x - p[1][2].y;
                lh[2] = s0 - s1; hl[2] = d0 + d1; hh[2] = d0 - d1;
                llv2 = (s0 + s1) * 0.5f;
            }

            // LL1: level-1 row r=2I-1+a (a>=1), cols {2J, 2J+1}
            if (a >= 1) {
                float2 w2; w2.x = llv1; w2.y = llv2;
                *reinterpret_cast<float2*>(llc + (size_t)(2 * I - 1 + a) * 256 + 2 * J) = w2;
            }

            const float* wg = wch + a * 81;
#pragma unroll
            for (int q = 0; q < 3; ++q) {
                const float* w0 = wg + q * 27;   // 27 consecutive uniform weights
#pragma unroll
                for (int o = 0; o < 9; ++o) acc[o] += lh[q] * w0[o];
#pragma unroll
                for (int o = 0; o < 9; ++o) acc[o] += hl[q] * w0[9 + o];
#pragma unroll
                for (int o = 0; o < 9; ++o) acc[o] += hh[q] * w0[18 + o];
            }
        }
        if (ch < 2) __syncthreads();          // drains prefetch AFTER compute
    }

#pragma unroll
    for (int o = 0; o < 9; ++o)
        y[(((size_t)b * 9 + o) * 128 + I) * 128 + J] = acc[o];
}

// K2: one block = one batch image, a 32x32 tile at 256-res (=> 64x64 output
// pixels at 512-res), all 3 colors. Each thread owns a 2x2 parity quad; all
// 36 accumulators live (needs VGPR room -> launch_bounds(256,4)).
__global__ __launch_bounds__(256, 4) void k2_up_idwt(
    const float* __restrict__ yg,    // (B,9,128,128)
    const float* __restrict__ wu,    // reordered (cin,rt,ct,di,dj,o)
    const float* __restrict__ ub,    // (9)
    const float* __restrict__ LL1,   // (B,3,256,256)
    float* __restrict__ out)         // (B,3,512,512)
{
    __shared__ float ysh[9][18][19];

    const int t    = threadIdx.x;
    const int b    = blockIdx.x >> 6;
    const int tile = blockIdx.x & 63;
    const int r0   = (tile >> 3) << 5;  // 256-res tile origin
    const int c0   = (tile & 7) << 5;
    const int p0   = (r0 >> 1) - 1;     // y row of local 0
    const int q0   = (c0 >> 1) - 1;

    // ---- stage y tile (18x18 halo, 9 ch) into LDS ----
    for (int item = t; item < 9 * 324; item += 256) {
        const int cin = item / 324;
        int rem       = item - cin * 324;
        const int lp  = rem / 18;
        const int lq  = rem - lp * 18;
        const int p   = p0 + lp, q = q0 + lq;
        float v = 0.f;
        if (p >= 0 && p < 128 && q >= 0 && q < 128)
            v = yg[(((size_t)b * 9 + cin) * 128 + p) * 128 + q];
        ysh[cin][lp][lq] = v;
    }
    __syncthreads();

    const int i2 = t >> 4;   // 0..15
    const int j2 = t & 15;   // 0..15

    float acc[2][2][9];      // [di][dj][out-ch]
#pragma unroll
    for (int di = 0; di < 2; ++di)
#pragma unroll
        for (int dj = 0; dj < 2; ++dj)
#pragma unroll
            for (int o = 0; o < 9; ++o) acc[di][dj][o] = ub[o];

    for (int cin = 0; cin < 9; ++cin) {
        float yv[3][3];
#pragma unroll
        for (int r = 0; r < 3; ++r)
#pragma unroll
            for (int c = 0; c < 3; ++c)
                yv[r][c] = ysh[cin][i2 + r][j2 + c];
        const float* wc = wu + cin * 144;
#pragma unroll
        for (int rt = 0; rt < 2; ++rt)
#pragma unroll
            for (int ct = 0; ct < 2; ++ct) {
                const float* wg = wc + (rt * 2 + ct) * 36;  // 36 consecutive
#pragma unroll
                for (int di = 0; di < 2; ++di)
#pragma unroll
                    for (int dj = 0; dj < 2; ++dj) {
                        const float vv = yv[di + rt][dj + ct];
                        const float* w9 = wg + (di * 2 + dj) * 9;
#pragma unroll
                        for (int o = 0; o < 9; ++o)
                            acc[di][dj][o] += vv * w9[o];
                    }
            }
    }

    // ---- epilogue: idwt2(LL1, LH, HL, HH) -> 4x4 output pixels / color ----
#pragma unroll
    for (int cc = 0; cc < 3; ++cc) {
#pragma unroll
        for (int di = 0; di < 2; ++di) {
            const int I = r0 + 2 * i2 + di;
            const int J = c0 + 2 * j2;
            const float2 llv = *reinterpret_cast<const float2*>(
                LL1 + (((size_t)b * 3 + cc) * 256 + I) * 256 + J);
            float4 top, bot;
            {
                const float ll = llv.x;
                const float lh = acc[di][0][cc * 3 + 0];
                const float hl = acc[di][0][cc * 3 + 1];
                const float hh = acc[di][0][cc * 3 + 2];
                const float e0 = ll + lh, od0 = ll - lh;
                const float e1 = hl + hh, od1 = hl - hh;
                top.x = (e0 + e1) * 0.5f; top.y = (e0 - e1) * 0.5f;
                bot.x = (od0 + od1) * 0.5f; bot.y = (od0 - od1) * 0.5f;
            }
            {
                const float ll = llv.y;
                const float lh = acc[di][1][cc * 3 + 0];
                const float hl = acc[di][1][cc * 3 + 1];
                const float hh = acc[di][1][cc * 3 + 2];
                const float e0 = ll + lh, od0 = ll - lh;
                const float e1 = hl + hh, od1 = hl - hh;
                top.z = (e0 + e1) * 0.5f; top.w = (e0 - e1) * 0.5f;
                bot.z = (od0 + od1) * 0.5f; bot.w = (od0 - od1) * 0.5f;
            }
            float* op = out + (((size_t)b * 3 + cc) * 512 + 2 * I) * 512 + 2 * J;
            *reinterpret_cast<float4*>(op) = top;
            *reinterpret_cast<float4*>(op + 512) = bot;
        }
    }
}

extern "C" void kernel_launch(void* const* d_in, const int* in_sizes, int n_in,
                              void* d_out, int out_size, void* d_ws, size_t ws_size,
                              hipStream_t stream) {
    const float* x  = (const float*)d_in[0];
    const float* dw = (const float*)d_in[1];
    const float* db = (const float*)d_in[2];
    const float* uw = (const float*)d_in[3];
    const float* ub = (const float*)d_in[4];
    float* outp = (float*)d_out;

    float* wsf = (float*)d_ws;
    float* wd  = wsf;            // 729 floats (pad to 768)
    float* wu  = wsf + 768;      // 1296 floats (768+1296=2064)
    float* zp  = wsf + 2240;     // 16-float zero page (16B aligned)
    float* LL1 = wsf + 2304;                         // 25.2 MB
    float* y   = LL1 + (size_t)BB * 3 * 256 * 256;   // 18.9 MB

    k0_rearrange<<<dim3(1), dim3(256), 0, stream>>>(dw, uw, wd, wu, zp);
    k1_dwt_down<<<dim3(BB * 64), dim3(256), 0, stream>>>(x, wd, db, zp, LL1, y);
    k2_up_idwt<<<dim3(BB * 64), dim3(256), 0, stream>>>(y, wu, ub, LL1, outp);
}